// Round 7
// baseline (131.545 us; speedup 1.0000x reference)
//
#include <hip/hip_runtime.h>
#include <hip/hip_bf16.h>

// Problem constants (fixed by the reference).
#define N_NODES 10000
#define DEG     32
#define CH      16
#define IN_DIM  4
#define BATCH   8
#define E_EDGES (N_NODES * DEG)        // 320000
#define WI_STRIDE (E_EDGES * CH)       // 5,120,000 floats between w[i] planes
#define P_COUNT 625                    // 512*625 == E_EDGES : gather period in n
#define LX_STRIDE 36                   // 32 floats/row + 4 pad (16B-aligned)

// Kernel 1: transpose/pad x[B][N][4] -> xt[N+1][B][4] (node-major, 128 B/node).
__global__ __launch_bounds__(256) void lcg_transpose(const float* __restrict__ x,
                                                     float* __restrict__ xt) {
    int t = blockIdx.x * 256 + threadIdx.x;
    if (t < BATCH * N_NODES) {
        int b = t / N_NODES;
        int node = t - b * N_NODES;
        float4 v = *(const float4*)(x + 4 * t);          // x[b][node][0..3]
        *(float4*)(xt + node * 32 + b * 4) = v;
    } else if (t < BATCH * N_NODES + 8) {
        int r = t - BATCH * N_NODES;                     // zero pad row N_NODES
        *(float4*)(xt + N_NODES * 32 + r * 4) = make_float4(0.f, 0.f, 0.f, 0.f);
    }
}

// Kernel 2: one block per p (0..624), 512 threads = 8 waves.
// Wave wv handles TWO node groups j = wv and wv+8 (n = p + 625 j): the x-row
// registers (8 float4 from LDS) are reused for both j's weights -> LDS read
// traffic halves vs r6 (655 -> 328 MB), which was the binding pipe.
// Weight loads stay 64-float-contiguous per wave instruction (the r6 win):
// lane = c + 16*dq, address = base + n*512 + 64*ds + lane.
__global__ __launch_bounds__(512, 4) void lcg_main(
    const float* __restrict__ xt,     // [N+1][32]
    const int*   __restrict__ edges,  // [E]
    const float* __restrict__ w,      // [4][E][16]
    float*       __restrict__ out)    // [8][N][16]
{
    __shared__ float lx[512 * LX_STRIDE];   // 73728 B -> 2 blocks/CU, 16 waves/CU

    int p = blockIdx.x;
    int t = threadIdx.x;

    // ---- Stage A: edges + gather into LDS (rows s = 0..511) ----
    {
        int sub = t & 7;              // which float4 of the 128 B node row
        int rg  = t >> 3;             // 0..63 ; rows s = rg + 64k, k<8
        const int* ep = edges + 512 * p;
        int nd[8];
#pragma unroll
        for (int k = 0; k < 8; k++) nd[k] = ep[rg + 64 * k];
#pragma unroll
        for (int k = 0; k < 8; k++) {
            int s = rg + 64 * k;
            float4 v = *(const float4*)(xt + nd[k] * 32 + sub * 4);
            *(float4*)(&lx[s * LX_STRIDE + sub * 4]) = v;
        }
    }
    __syncthreads();

    // ---- Stage B ----
    int lane = t & 63;
    int wv   = t >> 6;                // 0..7
    int c    = lane & 15;
    int dq   = lane >> 4;             // 0..3 : handles d = 4*ds + dq
    int n0   = p + P_COUNT * wv;      // j = wv
    int n1   = n0 + P_COUNT * 8;      // j = wv + 8

    const float* wb0 = w + n0 * (DEG * CH) + lane;   // 64-contiguous per wave
    const float* wb1 = w + n1 * (DEG * CH) + lane;

    float accA[BATCH], accB[BATCH];   // j0, j1
#pragma unroll
    for (int b = 0; b < BATCH; b++) { accA[b] = 0.f; accB[b] = 0.f; }

    const float* lrow = &lx[(16 * dq + c) * LX_STRIDE];

#pragma unroll 2
    for (int ds = 0; ds < 8; ds++) {
        float wa0 = wb0[64 * ds];
        float wa1 = wb0[64 * ds + WI_STRIDE];
        float wa2 = wb0[64 * ds + 2 * WI_STRIDE];
        float wa3 = wb0[64 * ds + 3 * WI_STRIDE];
        float wc0 = wb1[64 * ds];
        float wc1 = wb1[64 * ds + WI_STRIDE];
        float wc2 = wb1[64 * ds + 2 * WI_STRIDE];
        float wc3 = wb1[64 * ds + 3 * WI_STRIDE];
        const float* lr = lrow + ds * (64 * LX_STRIDE);
#pragma unroll
        for (int b = 0; b < BATCH; b++) {
            float4 xq = *(const float4*)(lr + 4 * b);   // read ONCE, used 2x
            accA[b] += xq.x * wa0 + xq.y * wa1 + xq.z * wa2 + xq.w * wa3;
            accB[b] += xq.x * wc0 + xq.y * wc1 + xq.z * wc2 + xq.w * wc3;
        }
    }

    // reduce over dq groups (lanes l, l^16, l^32, l^48)
#pragma unroll
    for (int b = 0; b < BATCH; b++) {
        accA[b] += __shfl_xor(accA[b], 16, 64);
        accA[b] += __shfl_xor(accA[b], 32, 64);
        accB[b] += __shfl_xor(accB[b], 16, 64);
        accB[b] += __shfl_xor(accB[b], 32, 64);
    }

    // dq group g stores batches {2g, 2g+1} for both j's (16 c-lanes = 64 B/line)
    int ob0 = n0 * CH + c;
    int ob1 = n1 * CH + c;
    out[(2 * dq + 0) * (N_NODES * CH) + ob0] = accA[2 * dq + 0];
    out[(2 * dq + 1) * (N_NODES * CH) + ob0] = accA[2 * dq + 1];
    out[(2 * dq + 0) * (N_NODES * CH) + ob1] = accB[2 * dq + 0];
    out[(2 * dq + 1) * (N_NODES * CH) + ob1] = accB[2 * dq + 1];
}

extern "C" void kernel_launch(void* const* d_in, const int* in_sizes, int n_in,
                              void* d_out, int out_size, void* d_ws, size_t ws_size,
                              hipStream_t stream) {
    const float* x     = (const float*)d_in[0];   // [8][10000][4] f32
    const int*   edges = (const int*)d_in[1];     // [320000] int
    const float* w     = (const float*)d_in[2];   // [4][320000][16] f32
    float* out = (float*)d_out;                   // [8][10000][16] f32
    float* xt  = (float*)d_ws;                    // (10001*32) floats = 1.28 MB

    int tr_total  = BATCH * N_NODES + 8;                  // 80008
    int tr_blocks = (tr_total + 255) / 256;               // 313
    lcg_transpose<<<tr_blocks, 256, 0, stream>>>(x, xt);

    lcg_main<<<P_COUNT, 512, 0, stream>>>(xt, edges, w, out);
}

// Round 8
// 130.487 us; speedup vs baseline: 1.0081x; 1.0081x over previous
//
#include <hip/hip_runtime.h>
#include <hip/hip_bf16.h>

// Problem constants (fixed by the reference).
#define N_NODES 10000
#define DEG     32
#define CH      16
#define IN_DIM  4
#define BATCH   8
#define E_EDGES (N_NODES * DEG)        // 320000
#define WI_STRIDE (E_EDGES * CH)       // 5,120,000 floats between w[i] planes
#define P_COUNT 625                    // 512*625 == E_EDGES : gather period in n
#define LX_STRIDE 36                   // 32 floats/row + 4 pad (16B-aligned)

// Kernel 1: transpose/pad x[B][N][4] -> xt[N+1][B][4] (node-major, 128 B/node).
__global__ __launch_bounds__(256) void lcg_transpose(const float* __restrict__ x,
                                                     float* __restrict__ xt) {
    int t = blockIdx.x * 256 + threadIdx.x;
    if (t < BATCH * N_NODES) {
        int b = t / N_NODES;
        int node = t - b * N_NODES;
        float4 v = *(const float4*)(x + 4 * t);          // x[b][node][0..3]
        *(float4*)(xt + node * 32 + b * 4) = v;
    } else if (t < BATCH * N_NODES + 8) {
        int r = t - BATCH * N_NODES;                     // zero pad row N_NODES
        *(float4*)(xt + N_NODES * 32 + r * 4) = make_float4(0.f, 0.f, 0.f, 0.f);
    }
}

// Kernel 2: block = (p, j-half). 512 threads = 8 waves; wave wv owns
// j = 8*jh + wv (n = p + 625*j). Outputs across jh are DISJOINT (no partial
// buffers, unlike the r5 d-split) and weight loads stay 64-float contiguous
// per wave instruction (the r6 win). 1250 blocks at 2/CU -> 4-5 blocks per CU
// (2.5% imbalance) vs r6's 625 blocks -> 2-3 per CU (23% imbalance).
// Cost: stage-A gather duplicated across the two jh blocks (~41 MB extra
// L2-resident reads, overlapped).
__global__ __launch_bounds__(512, 4) void lcg_main(
    const float* __restrict__ xt,     // [N+1][32]
    const int*   __restrict__ edges,  // [E]
    const float* __restrict__ w,      // [4][E][16]
    float*       __restrict__ out)    // [8][N][16]
{
    __shared__ float lx[512 * LX_STRIDE];   // 73728 B -> 2 blocks/CU, 16 waves/CU

    int bid = blockIdx.x;
    int p   = bid >> 1;               // 0..624
    int jh  = bid & 1;                // j-half
    int t   = threadIdx.x;

    // ---- Stage A: edges + gather into LDS (rows s = 0..511) ----
    {
        int sub = t & 7;              // which float4 of the 128 B node row
        int rg  = t >> 3;             // 0..63 ; rows s = rg + 64k, k<8
        const int* ep = edges + 512 * p;
        int nd[8];
#pragma unroll
        for (int k = 0; k < 8; k++) nd[k] = ep[rg + 64 * k];
#pragma unroll
        for (int k = 0; k < 8; k++) {
            int s = rg + 64 * k;
            float4 v = *(const float4*)(xt + nd[k] * 32 + sub * 4);
            *(float4*)(&lx[s * LX_STRIDE + sub * 4]) = v;
        }
    }
    __syncthreads();

    // ---- Stage B (identical math to r6, one j per wave) ----
    int lane = t & 63;
    int wv   = t >> 6;                // 0..7
    int c    = lane & 15;
    int dq   = lane >> 4;             // 0..3 : handles d = 4*ds + dq
    int j    = 8 * jh + wv;
    int n    = p + P_COUNT * j;

    // weight address: w[i][32n + (4ds+dq)][c] = base_i + n*512 + 64*ds + lane
    // -> 64 CONSECUTIVE floats per wave load (256 B, 4 full lines).
    const float* wb = w + n * (DEG * CH) + lane;

    float acc[BATCH];
#pragma unroll
    for (int b = 0; b < BATCH; b++) acc[b] = 0.0f;

    const float* lrow = &lx[(16 * dq + c) * LX_STRIDE];

#pragma unroll 2
    for (int ds = 0; ds < 8; ds++) {
        float w0 = wb[64 * ds];
        float w1 = wb[64 * ds + WI_STRIDE];
        float w2 = wb[64 * ds + 2 * WI_STRIDE];
        float w3 = wb[64 * ds + 3 * WI_STRIDE];
        const float* lr = lrow + ds * (64 * LX_STRIDE);
#pragma unroll
        for (int b = 0; b < BATCH; b++) {
            float4 xq = *(const float4*)(lr + 4 * b);
            acc[b] += xq.x * w0 + xq.y * w1 + xq.z * w2 + xq.w * w3;
        }
    }

    // reduce over dq groups (lanes l, l^16, l^32, l^48)
#pragma unroll
    for (int b = 0; b < BATCH; b++) {
        acc[b] += __shfl_xor(acc[b], 16, 64);
        acc[b] += __shfl_xor(acc[b], 32, 64);
    }

    // dq group g stores batches {2g, 2g+1} (16 c-lanes = one 64 B line per b)
    int ob = n * CH + c;
    out[(2 * dq + 0) * (N_NODES * CH) + ob] = acc[2 * dq + 0];
    out[(2 * dq + 1) * (N_NODES * CH) + ob] = acc[2 * dq + 1];
}

extern "C" void kernel_launch(void* const* d_in, const int* in_sizes, int n_in,
                              void* d_out, int out_size, void* d_ws, size_t ws_size,
                              hipStream_t stream) {
    const float* x     = (const float*)d_in[0];   // [8][10000][4] f32
    const int*   edges = (const int*)d_in[1];     // [320000] int
    const float* w     = (const float*)d_in[2];   // [4][320000][16] f32
    float* out = (float*)d_out;                   // [8][10000][16] f32
    float* xt  = (float*)d_ws;                    // (10001*32) floats = 1.28 MB

    int tr_total  = BATCH * N_NODES + 8;                  // 80008
    int tr_blocks = (tr_total + 255) / 256;               // 313
    lcg_transpose<<<tr_blocks, 256, 0, stream>>>(x, xt);

    lcg_main<<<2 * P_COUNT, 512, 0, stream>>>(xt, edges, w, out);
}